// Round 4
// baseline (1867.952 us; speedup 1.0000x reference)
//
#include <hip/hip_runtime.h>
#include <math.h>

typedef __attribute__((ext_vector_type(8))) __bf16 bf16x8;
typedef __attribute__((ext_vector_type(4))) float f32x4;
typedef unsigned short u16;
typedef unsigned int u32;

#define MFMA16(a, b, c) __builtin_amdgcn_mfma_f32_16x16x32_bf16(a, b, c, 0, 0, 0)

__device__ __forceinline__ u16 f2bf(float f) {
    u32 u = __float_as_uint(f);
    return (u16)((u + 0x7fffu + ((u >> 16) & 1u)) >> 16);   // RNE
}
__device__ __forceinline__ float bf2f(u16 h) {
    return __uint_as_float(((u32)h) << 16);
}

// ---------------------------------------------------------------------------
// conv weights fp32 [oc][ic][ky][kx] -> bf16 hi/lo [s][oc'][ic] where
// oc' = q*32 + cc*4 + g  (orig oc = g*64 + q*8 + cc) -> each thread's f32x4
// accumulator ends up holding all 4 gates of one channel.
__global__ __launch_bounds__(256) void k_wtrans2(const float* __restrict__ cw,
                                                 u16* __restrict__ whi,
                                                 u16* __restrict__ wlo) {
    int idx = blockIdx.x * 256 + threadIdx.x;
    if (idx >= 294912) return;
    int s   = idx >> 15;
    int ocp = (idx >> 7) & 255;
    int ic  = idx & 127;
    int q = ocp >> 5, cc = (ocp >> 2) & 7, g = ocp & 3;
    int oc = g * 64 + q * 8 + cc;
    float f = cw[oc * 1152 + ic * 9 + s];
    u16 hi = f2bf(f);
    whi[idx] = hi;
    wlo[idx] = f2bf(f - bf2f(hi));
}

// ---------------------------------------------------------------------------
// QKV for ALL (b,t).  qmat/kmat: [bt][n][d] bf16 (d contig). vt: [bt][c][m] bf16.
__global__ __launch_bounds__(256) void k_qkv(
    const float* __restrict__ X,
    const float* __restrict__ qw, const float* __restrict__ qb,
    const float* __restrict__ kw, const float* __restrict__ kb,
    const float* __restrict__ vw, const float* __restrict__ vb,
    u16* __restrict__ qmat, u16* __restrict__ kmat, u16* __restrict__ vt)
{
    __shared__ float sbuf[4096];
    const int tid    = threadIdx.x;
    const int ntile  = blockIdx.x;   // 0..15
    const int bt     = blockIdx.y;   // b*16 + t
    const int osplit = blockIdx.z;   // 0..3
    const int b = bt >> 4, t = bt & 15;

    const float* xbase = X + (size_t)b * 1048576 + (size_t)t * 1024 + ntile * 64;
    for (int i = tid; i < 4096; i += 256) {
        int c = i >> 6, n = i & 63;
        sbuf[c * 64 + n] = xbase[(size_t)c * 16384 + n];
    }
    __syncthreads();

    const int og = __builtin_amdgcn_readfirstlane(tid >> 6);
    const int n  = tid & 63;
    const int o0 = osplit * 48 + og * 12;

    float acc[12];
#pragma unroll
    for (int j = 0; j < 12; ++j) acc[j] = 0.f;

    for (int c0 = 0; c0 < 64; c0 += 16) {
        float xv[16];
#pragma unroll
        for (int cc = 0; cc < 16; ++cc) xv[cc] = sbuf[(c0 + cc) * 64 + n];
#pragma unroll
        for (int j = 0; j < 12; ++j) {
            int o = o0 + j;
            const float* wrow = (o < 64) ? (qw + o * 64)
                              : (o < 128) ? (kw + (o - 64) * 64)
                                          : (vw + (o - 128) * 64);
#pragma unroll
            for (int cc = 0; cc < 16; ++cc) acc[j] += wrow[c0 + cc] * xv[cc];
        }
    }

#pragma unroll
    for (int j = 0; j < 12; ++j) {
        int o = o0 + j;
        if (o >= 128)
            vt[(size_t)bt * 65536 + (o - 128) * 1024 + ntile * 64 + n] =
                f2bf(acc[j] + vb[o - 128]);
    }
    __syncthreads();
#pragma unroll
    for (int j = 0; j < 12; ++j) {
        int o = o0 + j;
        if (o < 128) {
            float bias = (o < 64) ? qb[o] : kb[o - 64];
            sbuf[(og * 12 + j) * 65 + n] = acc[j] + bias;
        }
    }
    __syncthreads();

    if (osplit < 3) {
        const int tn = tid >> 2, oq = tid & 3;
#pragma unroll
        for (int k = 0; k < 6; ++k) {
            int o_l = oq * 12 + k * 2;
            int o_g = osplit * 48 + o_l;
            if (o_g < 128) {
                u32 pk = (u32)f2bf(sbuf[o_l * 65 + tn]) |
                         ((u32)f2bf(sbuf[(o_l + 1) * 65 + tn]) << 16);
                u16* base = (o_g < 64)
                    ? (qmat + (size_t)bt * 65536 + (ntile * 64 + tn) * 64 + o_g)
                    : (kmat + (size_t)bt * 65536 + (ntile * 64 + tn) * 64 + (o_g - 64));
                *reinterpret_cast<u32*>(base) = pk;
            }
        }
    }
}

// ---------------------------------------------------------------------------
// MFMA attention with LDS-staged K/V tiles (XOR-swizzled) + next-tile prefetch.
// Output: za padded [bt][34][34][128] (ch 0-63 = hi, 64-127 = lo), ring = 0.
__global__ __launch_bounds__(256, 4) void k_attn(
    const u16* __restrict__ qmat, const u16* __restrict__ kmat,
    const u16* __restrict__ vt, u16* __restrict__ za)
{
    __shared__ char kl[16384];          // K tile [128 m][64 d] swizzled
    __shared__ char vl[16384];          // V tile [64 c][128 m] swizzled
    __shared__ u16 plds[4 * 16 * 40];   // per-wave P [16 n][40 m-stride]

    const int tid = threadIdx.x;
    const int id  = blockIdx.x;                 // 0..2047
    const int w   = (id & 7) * 256 + (id >> 3); // XCD-contiguous bt runs
    const int bt  = w >> 4;
    const int ntile = w & 15;

    const int wv = tid >> 6, lane = tid & 63;
    const int l15 = lane & 15, l4 = lane >> 4;
    const int n0 = ntile * 64 + wv * 16;

    const u16* qb_ = qmat + (size_t)bt * 65536;
    const u16* kb_ = kmat + (size_t)bt * 65536;
    const u16* vb_ = vt + (size_t)bt * 65536;

    bf16x8 qf0 = *reinterpret_cast<const bf16x8*>(qb_ + (n0 + l15) * 64 + l4 * 8);
    bf16x8 qf1 = *reinterpret_cast<const bf16x8*>(qb_ + (n0 + l15) * 64 + 32 + l4 * 8);

    f32x4 oacc[4];
#pragma unroll
    for (int ct = 0; ct < 4; ++ct) oacc[ct] = (f32x4){0.f, 0.f, 0.f, 0.f};
    float lsum = 0.f;
    char* plc = (char*)plds + wv * 1280;

    bf16x8 kst[4], vst[4];
    // prologue: load tile 0 to regs
#pragma unroll
    for (int r = 0; r < 4; ++r) {
        int c = tid + r * 256;
        kst[r] = *reinterpret_cast<const bf16x8*>(kb_ + (c >> 3) * 64 + (c & 7) * 8);
        vst[r] = *reinterpret_cast<const bf16x8*>(vb_ + (c >> 4) * 1024 + (c & 15) * 8);
    }

    for (int mt = 0; mt < 8; ++mt) {
        __syncthreads();   // previous tile's LDS reads done
#pragma unroll
        for (int r = 0; r < 4; ++r) {
            int c = tid + r * 256;
            int m = c >> 3, sl = c & 7;
            *reinterpret_cast<bf16x8*>(kl + ((m * 128 + sl * 16) ^ ((m & 7) << 4))) = kst[r];
            int cc = c >> 4, sl2 = c & 15;
            *reinterpret_cast<bf16x8*>(vl + ((cc * 256 + sl2 * 16) ^ ((cc & 7) << 4))) = vst[r];
        }
        __syncthreads();
        if (mt < 7) {   // prefetch next tile during compute
            int mg = (mt + 1) * 128;
#pragma unroll
            for (int r = 0; r < 4; ++r) {
                int c = tid + r * 256;
                kst[r] = *reinterpret_cast<const bf16x8*>(kb_ + (mg + (c >> 3)) * 64 + (c & 7) * 8);
                vst[r] = *reinterpret_cast<const bf16x8*>(vb_ + (c >> 4) * 1024 + mg + (c & 15) * 8);
            }
        }

#pragma unroll
        for (int mi2 = 0; mi2 < 4; ++mi2) {
#pragma unroll
            for (int hf = 0; hf < 2; ++hf) {
                int ml = (mi2 * 2 + hf) * 16 + l15;
                f32x4 s = {0.f, 0.f, 0.f, 0.f};
                bf16x8 ka0 = *reinterpret_cast<const bf16x8*>(
                    kl + ((ml * 128 + l4 * 16) ^ ((ml & 7) << 4)));
                bf16x8 ka1 = *reinterpret_cast<const bf16x8*>(
                    kl + ((ml * 128 + 64 + l4 * 16) ^ ((ml & 7) << 4)));
                s = MFMA16(ka0, qf0, s);
                s = MFMA16(ka1, qf1, s);
                float p0 = __expf(s[0]);
                float p1 = __expf(s[1]);
                float p2 = __expf(s[2]);
                float p3 = __expf(s[3]);
                lsum += (p0 + p1) + (p2 + p3);
                u32 pa = (u32)f2bf(p0) | ((u32)f2bf(p1) << 16);
                u32 pb = (u32)f2bf(p2) | ((u32)f2bf(p3) << 16);
                *reinterpret_cast<uint2*>(plc + l15 * 80 + hf * 32 + l4 * 8) =
                    make_uint2(pa, pb);
            }
            bf16x8 pfrag = *reinterpret_cast<const bf16x8*>(plc + l15 * 80 + l4 * 16);
#pragma unroll
            for (int ct = 0; ct < 4; ++ct) {
                bf16x8 vfrag = *reinterpret_cast<const bf16x8*>(
                    vl + (((ct * 16 + l15) * 256 + mi2 * 64 + l4 * 16) ^ ((l15 & 7) << 4)));
                oacc[ct] = MFMA16(pfrag, vfrag, oacc[ct]);
            }
        }
    }

    lsum += __shfl_xor(lsum, 16, 64);
    lsum += __shfl_xor(lsum, 32, 64);

    u16* zab = za + (size_t)bt * 147968;
#pragma unroll
    for (int r = 0; r < 4; ++r) {
        float linv = 1.f / __shfl(lsum, l4 * 4 + r, 64);
        int nrow = n0 + l4 * 4 + r;
        u16* base = zab + (((nrow >> 5) + 1) * 34 + (nrow & 31) + 1) * 128;
#pragma unroll
        for (int ct = 0; ct < 4; ++ct) {
            float v = oacc[ct][r] * linv;
            u16 hi = f2bf(v);
            base[ct * 16 + l15]      = hi;
            base[64 + ct * 16 + l15] = f2bf(v - bf2f(hi));
        }
    }
}

// ---------------------------------------------------------------------------
// Fused conv+gates, NO LDS staging: B-fragments direct from padded hi/lo
// global tensors (L1/L2-resident). Block = 2 rows x 8 ch; 1024 blocks.
__global__ __launch_bounds__(256) void k_cell(
    const u16* __restrict__ za, const u16* __restrict__ zh_in,
    u16* __restrict__ zh_out, float* __restrict__ cst,
    const u16* __restrict__ whi, const u16* __restrict__ wlo,
    const float* __restrict__ conv_b,
    const float* __restrict__ wci, const float* __restrict__ wcf,
    const float* __restrict__ wco, float* __restrict__ out, int t)
{
    const int tid = threadIdx.x;
    const int id  = blockIdx.x;                  // 0..1023
    const int w   = (id & 7) * 128 + (id >> 3);  // each XCD owns one b
    const int b   = w >> 7;
    const int q   = (w >> 4) & 7;
    const int sb  = w & 15;

    const int wv = tid >> 6, lane = tid & 63;
    const int l15 = lane & 15, l4 = lane >> 4;
    const int bt = b * 16 + t;

    const int p = wv * 16 + l15;          // 0..63
    const int y = sb * 2 + (p >> 5);
    const int x = p & 31;

    const u16* zab = za + (size_t)bt * 147968;
    const u16* zhb = zh_in + (size_t)b * 147968;

    f32x4 acc[2];
    acc[0] = (f32x4){0.f, 0.f, 0.f, 0.f};
    acc[1] = (f32x4){0.f, 0.f, 0.f, 0.f};

#pragma unroll
    for (int ck = 0; ck < 4; ++ck) {
        const u16* zbase = (ck < 2) ? zab : zhb;
        const int c0 = (ck & 1) * 32;
#pragma unroll
        for (int s = 0; s < 9; ++s) {
            const int dy = s / 3 - 1, dx = s % 3 - 1;
            const u16* bp = zbase + ((y + dy + 1) * 34 + (x + dx + 1)) * 128 + c0 + l4 * 8;
            bf16x8 Bh = *reinterpret_cast<const bf16x8*>(bp);
            bf16x8 Bl = *reinterpret_cast<const bf16x8*>(bp + 64);
#pragma unroll
            for (int sub = 0; sub < 2; ++sub) {
                size_t woff = (size_t)(s * 256 + q * 32 + sub * 16 + l15) * 128 + ck * 32 + l4 * 8;
                bf16x8 Ah = *reinterpret_cast<const bf16x8*>(whi + woff);
                bf16x8 Al = *reinterpret_cast<const bf16x8*>(wlo + woff);
                acc[sub] = MFMA16(Ah, Bh, acc[sub]);
                acc[sub] = MFMA16(Ah, Bl, acc[sub]);
                acc[sub] = MFMA16(Al, Bh, acc[sub]);
            }
        }
    }

    // gates: C col = l15 -> px, row quad l4 -> ch = q*8 + sub*4 + l4, reg r = gate
    u16* zho = zh_out + (size_t)b * 147968;
    const int n = y * 32 + x;
#pragma unroll
    for (int sub = 0; sub < 2; ++sub) {
        int ch = q * 8 + sub * 4 + l4;
        float ci = acc[sub][0] + conv_b[ch];
        float cf = acc[sub][1] + conv_b[64 + ch];
        float cg = acc[sub][2] + conv_b[128 + ch];
        float co = acc[sub][3] + conv_b[192 + ch];
        size_t si = ((size_t)b * 64 + ch) * 1024 + n;
        int pw = ch * 1024 + n;
        float cp = cst[si];
        float iv = 1.f / (1.f + __expf(-(ci + wci[pw] * cp)));
        float fv = 1.f / (1.f + __expf(-(cf + wcf[pw] * cp)));
        float nc = fv * cp + iv * tanhf(cg);
        float ov = 1.f / (1.f + __expf(-(co + wco[pw] * nc)));
        float nh = ov * tanhf(nc);
        cst[si] = nc;
        out[(((size_t)b * 64 + ch) * 16 + t) * 1024 + n] = nh;
        u16 hhi = f2bf(nh);
        u16* zp = zho + ((y + 1) * 34 + (x + 1)) * 128;
        zp[ch]      = hhi;
        zp[64 + ch] = f2bf(nh - bf2f(hhi));
    }
}

// ---------------------------------------------------------------------------
// ws layout (bytes), total ~96.2 MB
#define OB_Q    0ull
#define OB_K    16777216ull
#define OB_V    33554432ull
#define OB_ZA   50331648ull   // 128 * 1156 * 128 * 2 = 37,879,808
#define OB_ZH0  88211456ull   // 8 * 1156 * 128 * 2 = 2,367,488
#define OB_ZH1  90578944ull
#define OB_CST  92946432ull   // 2,097,152
#define OB_WHI  95043584ull   // 589,824
#define OB_WLO  95633408ull   // 589,824

extern "C" void kernel_launch(void* const* d_in, const int* in_sizes, int n_in,
                              void* d_out, int out_size, void* d_ws, size_t ws_size,
                              hipStream_t stream)
{
    const float* X   = (const float*)d_in[0];
    const float* qw  = (const float*)d_in[1];
    const float* qb  = (const float*)d_in[2];
    const float* kw  = (const float*)d_in[3];
    const float* kb  = (const float*)d_in[4];
    const float* vw  = (const float*)d_in[5];
    const float* vb  = (const float*)d_in[6];
    const float* cw  = (const float*)d_in[7];
    const float* cb  = (const float*)d_in[8];
    const float* wci = (const float*)d_in[9];
    const float* wcf = (const float*)d_in[10];
    const float* wco = (const float*)d_in[11];
    float* out = (float*)d_out;
    char* wsb  = (char*)d_ws;

    u16* qmat = (u16*)(wsb + OB_Q);
    u16* kmat = (u16*)(wsb + OB_K);
    u16* vt   = (u16*)(wsb + OB_V);
    u16* za   = (u16*)(wsb + OB_ZA);
    u16* zh0  = (u16*)(wsb + OB_ZH0);
    u16* zh1  = (u16*)(wsb + OB_ZH1);
    float* cst= (float*)(wsb + OB_CST);
    u16* whi  = (u16*)(wsb + OB_WHI);
    u16* wlo  = (u16*)(wsb + OB_WLO);

    // zero ZA (pad ring) and ZH0/ZH1/cst (h0 = c0 = 0, rings = 0)
    hipMemsetAsync(za, 0, 37879808ull, stream);
    hipMemsetAsync(zh0, 0, 6832128ull, stream);   // zh0+zh1+cst contiguous
    k_wtrans2<<<1152, 256, 0, stream>>>(cw, whi, wlo);
    k_qkv<<<dim3(16, 128, 4), 256, 0, stream>>>(X, qw, qb, kw, kb, vw, vb,
                                                qmat, kmat, vt);
    k_attn<<<2048, 256, 0, stream>>>(qmat, kmat, vt, za);

    for (int t = 0; t < 16; ++t) {
        u16* hin  = (t & 1) ? zh1 : zh0;
        u16* hout = (t & 1) ? zh0 : zh1;
        k_cell<<<1024, 256, 0, stream>>>(za, hin, hout, cst, whi, wlo,
                                         cb, wci, wcf, wco, out, t);
    }
}

// Round 5
// 620.105 us; speedup vs baseline: 3.0123x; 3.0123x over previous
//
#include <hip/hip_runtime.h>
#include <math.h>

typedef __attribute__((ext_vector_type(8))) __bf16 bf16x8;
typedef __attribute__((ext_vector_type(4))) float f32x4;
typedef unsigned short u16;
typedef unsigned int u32;

#define MFMA16(a, b, c) __builtin_amdgcn_mfma_f32_16x16x32_bf16(a, b, c, 0, 0, 0)

__device__ __forceinline__ u16 f2bf(float f) {
    u32 u = __float_as_uint(f);
    return (u16)((u + 0x7fffu + ((u >> 16) & 1u)) >> 16);   // RNE
}
__device__ __forceinline__ float bf2f(u16 h) {
    return __uint_as_float(((u32)h) << 16);
}

// ---------------------------------------------------------------------------
// conv weights fp32 [oc][ic][ky][kx] -> bf16 hi/lo [s][oc'][ic] where
// oc' = q*32 + cc*4 + g  (orig oc = g*64 + q*8 + cc) -> each lane's f32x4
// accumulator holds all 4 gates of one channel.
__global__ __launch_bounds__(256) void k_wtrans2(const float* __restrict__ cw,
                                                 u16* __restrict__ whi,
                                                 u16* __restrict__ wlo) {
    int idx = blockIdx.x * 256 + threadIdx.x;
    if (idx >= 294912) return;
    int s   = idx >> 15;
    int ocp = (idx >> 7) & 255;
    int ic  = idx & 127;
    int q = ocp >> 5, cc = (ocp >> 2) & 7, g = ocp & 3;
    int oc = g * 64 + q * 8 + cc;
    float f = cw[oc * 1152 + ic * 9 + s];
    u16 hi = f2bf(f);
    whi[idx] = hi;
    wlo[idx] = f2bf(f - bf2f(hi));
}

// ---------------------------------------------------------------------------
// qkv weights fp32 -> bf16 hi/lo [o 0..191][c 0..63] (q rows 0-63, k 64-127, v 128-191)
__global__ __launch_bounds__(256) void k_qkvw(
    const float* __restrict__ qw, const float* __restrict__ kw,
    const float* __restrict__ vw, u16* __restrict__ w2h, u16* __restrict__ w2l)
{
    int idx = blockIdx.x * 256 + threadIdx.x;
    if (idx >= 12288) return;
    int o = idx >> 6, c = idx & 63;
    float f = (o < 64) ? qw[o * 64 + c]
            : (o < 128) ? kw[(o - 64) * 64 + c]
                        : vw[(o - 128) * 64 + c];
    u16 hi = f2bf(f);
    w2h[idx] = hi;
    w2l[idx] = f2bf(f - bf2f(hi));
}

// ---------------------------------------------------------------------------
// MFMA QKV: per block one (bt, 64-n slice). X split hi/lo in LDS (swizzled),
// W split hi/lo from global (L1-hot, 48KB). 3-MFMA split products.
__global__ __launch_bounds__(256) void k_qkv2(
    const float* __restrict__ X,
    const u16* __restrict__ w2h, const u16* __restrict__ w2l,
    const float* __restrict__ qb, const float* __restrict__ kb,
    const float* __restrict__ vb,
    u16* __restrict__ qmat, u16* __restrict__ kmat, u16* __restrict__ vt)
{
    __shared__ u16 bhs[4096];   // [n][c^((n&7)<<3)]
    __shared__ u16 bls[4096];

    const int tid = threadIdx.x;
    const int ns = blockIdx.x;    // 0..15
    const int bt = blockIdx.y;    // 0..127
    const int b = bt >> 4, t = bt & 15;
    const int n0 = ns * 64;

    const float* xb = X + (size_t)b * 1048576 + (size_t)t * 1024 + n0;
    for (int i = tid; i < 4096; i += 256) {
        int c = i >> 6, n = i & 63;
        float f = xb[(size_t)c * 16384 + n];
        u16 hi = f2bf(f);
        u16 lo = f2bf(f - bf2f(hi));
        int ci = c ^ ((n & 7) << 3);
        bhs[n * 64 + ci] = hi;
        bls[n * 64 + ci] = lo;
    }
    __syncthreads();

    const int wv = tid >> 6, lane = tid & 63;
    const int l15 = lane & 15, l4 = lane >> 4;
    const int o0 = wv * 48;

    f32x4 acc[3][4];
#pragma unroll
    for (int ot = 0; ot < 3; ++ot)
#pragma unroll
        for (int nt = 0; nt < 4; ++nt) acc[ot][nt] = (f32x4){0.f, 0.f, 0.f, 0.f};

#pragma unroll
    for (int kk = 0; kk < 2; ++kk) {
        bf16x8 Ah[3], Al[3];
#pragma unroll
        for (int ot = 0; ot < 3; ++ot) {
            int off = (o0 + ot * 16 + l15) * 64 + kk * 32 + l4 * 8;
            Ah[ot] = *reinterpret_cast<const bf16x8*>(w2h + off);
            Al[ot] = *reinterpret_cast<const bf16x8*>(w2l + off);
        }
#pragma unroll
        for (int nt = 0; nt < 4; ++nt) {
            int n = nt * 16 + l15;
            int gran = (kk * 4 + l4) ^ (n & 7);
            bf16x8 Bh = *reinterpret_cast<const bf16x8*>(bhs + n * 64 + gran * 8);
            bf16x8 Bl = *reinterpret_cast<const bf16x8*>(bls + n * 64 + gran * 8);
#pragma unroll
            for (int ot = 0; ot < 3; ++ot) {
                acc[ot][nt] = MFMA16(Ah[ot], Bh, acc[ot][nt]);
                acc[ot][nt] = MFMA16(Ah[ot], Bl, acc[ot][nt]);
                acc[ot][nt] = MFMA16(Al[ot], Bh, acc[ot][nt]);
            }
        }
    }

#pragma unroll
    for (int ot = 0; ot < 3; ++ot) {
#pragma unroll
        for (int r = 0; r < 4; ++r) {
            int row = o0 + ot * 16 + l4 * 4 + r;
            float bias = (row < 64) ? qb[row]
                       : (row < 128) ? kb[row - 64] : vb[row - 128];
#pragma unroll
            for (int nt = 0; nt < 4; ++nt) {
                int col = n0 + nt * 16 + l15;
                u16 h = f2bf(acc[ot][nt][r] + bias);
                if (row < 64)
                    qmat[(size_t)bt * 65536 + (size_t)col * 64 + row] = h;
                else if (row < 128)
                    kmat[(size_t)bt * 65536 + (size_t)col * 64 + (row - 64)] = h;
                else
                    vt[(size_t)bt * 65536 + (size_t)(row - 128) * 1024 + col] = h;
            }
        }
    }
}

// ---------------------------------------------------------------------------
// MFMA attention with LDS-staged K/V tiles (XOR-swizzled) + next-tile prefetch.
// Output: za padded [bt][34][34][128] (ch 0-63 = hi, 64-127 = lo), ring = 0.
__global__ __launch_bounds__(256, 4) void k_attn(
    const u16* __restrict__ qmat, const u16* __restrict__ kmat,
    const u16* __restrict__ vt, u16* __restrict__ za)
{
    __shared__ char kl[16384];          // K tile [128 m][64 d] swizzled
    __shared__ char vl[16384];          // V tile [64 c][128 m] swizzled
    __shared__ u16 plds[4 * 16 * 40];   // per-wave P [16 n][40 m-stride]

    const int tid = threadIdx.x;
    const int id  = blockIdx.x;                 // 0..2047
    const int w   = (id & 7) * 256 + (id >> 3); // XCD-contiguous bt runs
    const int bt  = w >> 4;
    const int ntile = w & 15;

    const int wv = tid >> 6, lane = tid & 63;
    const int l15 = lane & 15, l4 = lane >> 4;
    const int n0 = ntile * 64 + wv * 16;

    const u16* qb_ = qmat + (size_t)bt * 65536;
    const u16* kb_ = kmat + (size_t)bt * 65536;
    const u16* vb_ = vt + (size_t)bt * 65536;

    bf16x8 qf0 = *reinterpret_cast<const bf16x8*>(qb_ + (n0 + l15) * 64 + l4 * 8);
    bf16x8 qf1 = *reinterpret_cast<const bf16x8*>(qb_ + (n0 + l15) * 64 + 32 + l4 * 8);

    f32x4 oacc[4];
#pragma unroll
    for (int ct = 0; ct < 4; ++ct) oacc[ct] = (f32x4){0.f, 0.f, 0.f, 0.f};
    float lsum = 0.f;
    char* plc = (char*)plds + wv * 1280;

    bf16x8 kst[4], vst[4];
#pragma unroll
    for (int r = 0; r < 4; ++r) {
        int c = tid + r * 256;
        kst[r] = *reinterpret_cast<const bf16x8*>(kb_ + (c >> 3) * 64 + (c & 7) * 8);
        vst[r] = *reinterpret_cast<const bf16x8*>(vb_ + (c >> 4) * 1024 + (c & 15) * 8);
    }

    for (int mt = 0; mt < 8; ++mt) {
        __syncthreads();
#pragma unroll
        for (int r = 0; r < 4; ++r) {
            int c = tid + r * 256;
            int m = c >> 3, sl = c & 7;
            *reinterpret_cast<bf16x8*>(kl + ((m * 128 + sl * 16) ^ ((m & 7) << 4))) = kst[r];
            int cc = c >> 4, sl2 = c & 15;
            *reinterpret_cast<bf16x8*>(vl + ((cc * 256 + sl2 * 16) ^ ((cc & 7) << 4))) = vst[r];
        }
        __syncthreads();
        if (mt < 7) {
            int mg = (mt + 1) * 128;
#pragma unroll
            for (int r = 0; r < 4; ++r) {
                int c = tid + r * 256;
                kst[r] = *reinterpret_cast<const bf16x8*>(kb_ + (mg + (c >> 3)) * 64 + (c & 7) * 8);
                vst[r] = *reinterpret_cast<const bf16x8*>(vb_ + (c >> 4) * 1024 + mg + (c & 15) * 8);
            }
        }

#pragma unroll
        for (int mi2 = 0; mi2 < 4; ++mi2) {
#pragma unroll
            for (int hf = 0; hf < 2; ++hf) {
                int ml = (mi2 * 2 + hf) * 16 + l15;
                f32x4 s = {0.f, 0.f, 0.f, 0.f};
                bf16x8 ka0 = *reinterpret_cast<const bf16x8*>(
                    kl + ((ml * 128 + l4 * 16) ^ ((ml & 7) << 4)));
                bf16x8 ka1 = *reinterpret_cast<const bf16x8*>(
                    kl + ((ml * 128 + 64 + l4 * 16) ^ ((ml & 7) << 4)));
                s = MFMA16(ka0, qf0, s);
                s = MFMA16(ka1, qf1, s);
                float p0 = __expf(s[0]);
                float p1 = __expf(s[1]);
                float p2 = __expf(s[2]);
                float p3 = __expf(s[3]);
                lsum += (p0 + p1) + (p2 + p3);
                u32 pa = (u32)f2bf(p0) | ((u32)f2bf(p1) << 16);
                u32 pb = (u32)f2bf(p2) | ((u32)f2bf(p3) << 16);
                *reinterpret_cast<uint2*>(plc + l15 * 80 + hf * 32 + l4 * 8) =
                    make_uint2(pa, pb);
            }
            bf16x8 pfrag = *reinterpret_cast<const bf16x8*>(plc + l15 * 80 + l4 * 16);
#pragma unroll
            for (int ct = 0; ct < 4; ++ct) {
                bf16x8 vfrag = *reinterpret_cast<const bf16x8*>(
                    vl + (((ct * 16 + l15) * 256 + mi2 * 64 + l4 * 16) ^ ((l15 & 7) << 4)));
                oacc[ct] = MFMA16(pfrag, vfrag, oacc[ct]);
            }
        }
    }

    lsum += __shfl_xor(lsum, 16, 64);
    lsum += __shfl_xor(lsum, 32, 64);

    u16* zab = za + (size_t)bt * 147968;
#pragma unroll
    for (int r = 0; r < 4; ++r) {
        float linv = 1.f / __shfl(lsum, l4 * 4 + r, 64);
        int nrow = n0 + l4 * 4 + r;
        u16* base = zab + (((nrow >> 5) + 1) * 34 + (nrow & 31) + 1) * 128;
#pragma unroll
        for (int ct = 0; ct < 4; ++ct) {
            float v = oacc[ct][r] * linv;
            u16 hi = f2bf(v);
            base[ct * 16 + l15]      = hi;
            base[64 + ct * 16 + l15] = f2bf(v - bf2f(hi));
        }
    }
}

// ---------------------------------------------------------------------------
// Fused conv+gates, z staged in LDS per 32-ic chunk (XOR-swizzled), weights
// from global (L1-shared within block). Block = 64 ocp' x 128 px, 4 waves
// (wave = 32 ocp' x 64 px, acc[2][4]). Grid 256 = 4 oq x 8 b x 8 row-quads.
__global__ __launch_bounds__(256) void k_cell3(
    const u16* __restrict__ za, const u16* __restrict__ zh_in,
    u16* __restrict__ zh_out, float* __restrict__ cst,
    const u16* __restrict__ whi, const u16* __restrict__ wlo,
    const float* __restrict__ conv_b,
    const float* __restrict__ wci, const float* __restrict__ wcf,
    const float* __restrict__ wco, float* __restrict__ out, int t)
{
    __shared__ __align__(16) char zt[26112];   // [204 px][128B] swizzled

    const int tid = threadIdx.x;
    const int id  = blockIdx.x;          // 0..255
    const int pxt = id & 63;
    const int oq  = id >> 6;             // 0..3
    const int b   = pxt >> 3;
    const int y0  = (pxt & 7) * 4;
    const int bt  = b * 16 + t;

    const int wv = tid >> 6, lane = tid & 63;
    const int l15 = lane & 15, l4 = lane >> 4;
    const int ow = wv & 1, pw = wv >> 1;

    const u16* zab = za + (size_t)bt * 147968;
    const u16* zhb = zh_in + (size_t)b * 147968;

    f32x4 acc[2][4];
#pragma unroll
    for (int sub = 0; sub < 2; ++sub)
#pragma unroll
        for (int nt = 0; nt < 4; ++nt) acc[sub][nt] = (f32x4){0.f, 0.f, 0.f, 0.f};

    for (int ck = 0; ck < 4; ++ck) {
        const u16* src = (ck < 2) ? zab : zhb;
        const int c0 = (ck & 1) * 32;
        __syncthreads();   // previous chunk's reads done
        // stage 204 px rows x (32ch hi | 32ch lo), 16B granules, swizzled
        for (int g = tid; g < 1632; g += 256) {
            int p = g >> 3, slot = g & 7;
            int ly = p / 34, col = p - ly * 34;
            int gp = (y0 + ly) * 34 + col;          // padded global px index
            int soff = (slot < 4) ? (c0 + slot * 8) : (64 + c0 + (slot - 4) * 8);
            uint4 v = *reinterpret_cast<const uint4*>(src + gp * 128 + soff);
            *reinterpret_cast<uint4*>(zt + p * 128 + ((slot * 16) ^ ((p & 7) << 4))) = v;
        }
        __syncthreads();

#pragma unroll
        for (int s = 0; s < 9; ++s) {
            const int dy = s / 3 - 1, dx = s % 3 - 1;
            bf16x8 Ah[2], Al[2];
#pragma unroll
            for (int sub = 0; sub < 2; ++sub) {
                size_t woff = (size_t)(s * 256 + oq * 64 + ow * 32 + sub * 16 + l15) * 128
                              + ck * 32 + l4 * 8;
                Ah[sub] = *reinterpret_cast<const bf16x8*>(whi + woff);
                Al[sub] = *reinterpret_cast<const bf16x8*>(wlo + woff);
            }
#pragma unroll
            for (int nt = 0; nt < 4; ++nt) {
                int pxl = (pw * 2 + (nt >> 1) + 1 + dy) * 34 + (nt & 1) * 16 + l15 + 1 + dx;
                int swz = (pxl & 7) << 4;
                bf16x8 Bh = *reinterpret_cast<const bf16x8*>(
                    zt + pxl * 128 + ((l4 * 16) ^ swz));
                bf16x8 Bl = *reinterpret_cast<const bf16x8*>(
                    zt + pxl * 128 + ((64 + l4 * 16) ^ swz));
#pragma unroll
                for (int sub = 0; sub < 2; ++sub) {
                    acc[sub][nt] = MFMA16(Ah[sub], Bh, acc[sub][nt]);
                    acc[sub][nt] = MFMA16(Ah[sub], Bl, acc[sub][nt]);
                    acc[sub][nt] = MFMA16(Al[sub], Bh, acc[sub][nt]);
                }
            }
        }
    }

    // gates: acc[sub][nt] regs r = gates (i,f,g,o) of ch = (oq*2+ow)*8 + sub*4 + l4
    u16* zho = zh_out + (size_t)b * 147968;
    const int chq = (oq * 2 + ow) * 8;
#pragma unroll
    for (int sub = 0; sub < 2; ++sub) {
        int ch = chq + sub * 4 + l4;
        float bi = conv_b[ch], bf = conv_b[64 + ch];
        float bg = conv_b[128 + ch], bo = conv_b[192 + ch];
#pragma unroll
        for (int nt = 0; nt < 4; ++nt) {
            int y = y0 + pw * 2 + (nt >> 1);
            int x = (nt & 1) * 16 + l15;
            int n = y * 32 + x;
            float ci = acc[sub][nt][0] + bi;
            float cf = acc[sub][nt][1] + bf;
            float cg = acc[sub][nt][2] + bg;
            float co = acc[sub][nt][3] + bo;
            size_t si = ((size_t)b * 64 + ch) * 1024 + n;
            int pw_ = ch * 1024 + n;
            float cp = cst[si];
            float iv = 1.f / (1.f + __expf(-(ci + wci[pw_] * cp)));
            float fv = 1.f / (1.f + __expf(-(cf + wcf[pw_] * cp)));
            float nc = fv * cp + iv * tanhf(cg);
            float ov = 1.f / (1.f + __expf(-(co + wco[pw_] * nc)));
            float nh = ov * tanhf(nc);
            cst[si] = nc;
            out[(((size_t)b * 64 + ch) * 16 + t) * 1024 + n] = nh;
            u16 hhi = f2bf(nh);
            u16* zp = zho + ((y + 1) * 34 + (x + 1)) * 128;
            zp[ch]      = hhi;
            zp[64 + ch] = f2bf(nh - bf2f(hhi));
        }
    }
}

// ---------------------------------------------------------------------------
// ws layout (bytes), total ~96.3 MB (same budget as validated R4)
#define OB_Q    0ull
#define OB_K    16777216ull
#define OB_V    33554432ull
#define OB_ZA   50331648ull   // 128 * 1156 * 128 * 2 = 37,879,808
#define OB_ZH0  88211456ull   // 8 * 1156 * 128 * 2 = 2,367,488
#define OB_ZH1  90578944ull
#define OB_CST  92946432ull   // 2,097,152
#define OB_WHI  95043584ull   // 589,824
#define OB_WLO  95633408ull   // 589,824
#define OB_WQ2H 96223232ull   // 24,576
#define OB_WQ2L 96247808ull   // 24,576

extern "C" void kernel_launch(void* const* d_in, const int* in_sizes, int n_in,
                              void* d_out, int out_size, void* d_ws, size_t ws_size,
                              hipStream_t stream)
{
    const float* X   = (const float*)d_in[0];
    const float* qw  = (const float*)d_in[1];
    const float* qb  = (const float*)d_in[2];
    const float* kw  = (const float*)d_in[3];
    const float* kb  = (const float*)d_in[4];
    const float* vw  = (const float*)d_in[5];
    const float* vb  = (const float*)d_in[6];
    const float* cw  = (const float*)d_in[7];
    const float* cb  = (const float*)d_in[8];
    const float* wci = (const float*)d_in[9];
    const float* wcf = (const float*)d_in[10];
    const float* wco = (const float*)d_in[11];
    float* out = (float*)d_out;
    char* wsb  = (char*)d_ws;

    u16* qmat = (u16*)(wsb + OB_Q);
    u16* kmat = (u16*)(wsb + OB_K);
    u16* vt   = (u16*)(wsb + OB_V);
    u16* za   = (u16*)(wsb + OB_ZA);
    u16* zh0  = (u16*)(wsb + OB_ZH0);
    u16* zh1  = (u16*)(wsb + OB_ZH1);
    float* cst= (float*)(wsb + OB_CST);
    u16* whi  = (u16*)(wsb + OB_WHI);
    u16* wlo  = (u16*)(wsb + OB_WLO);
    u16* w2h  = (u16*)(wsb + OB_WQ2H);
    u16* w2l  = (u16*)(wsb + OB_WQ2L);

    hipMemsetAsync(za, 0, 37879808ull, stream);   // za pad ring
    hipMemsetAsync(zh0, 0, 6832128ull, stream);   // zh0 + zh1 + cst
    k_wtrans2<<<1152, 256, 0, stream>>>(cw, whi, wlo);
    k_qkvw<<<48, 256, 0, stream>>>(qw, kw, vw, w2h, w2l);
    k_qkv2<<<dim3(16, 128), 256, 0, stream>>>(X, w2h, w2l, qb, kb, vb,
                                              qmat, kmat, vt);
    k_attn<<<2048, 256, 0, stream>>>(qmat, kmat, vt, za);

    for (int t = 0; t < 16; ++t) {
        u16* hin  = (t & 1) ? zh1 : zh0;
        u16* hout = (t & 1) ? zh0 : zh1;
        k_cell3<<<256, 256, 0, stream>>>(za, hin, hout, cst, whi, wlo,
                                         cb, wci, wcf, wco, out, t);
    }
}